// Round 1
// baseline (875.069 us; speedup 1.0000x reference)
//
#include <hip/hip_runtime.h>

#define S_LEN 2048
#define DMODEL 1024
#define NH 16
#define DH 64
#define FFDIM 4096

typedef __bf16 bf16x8 __attribute__((ext_vector_type(8)));
typedef float f32x4 __attribute__((ext_vector_type(4)));
typedef unsigned short ushort_t;

__device__ __forceinline__ unsigned short f2b(float f){
  unsigned u = __builtin_bit_cast(unsigned, f);
  u = (u + 0x7FFFu + ((u >> 16) & 1u)) >> 16;
  return (unsigned short)u;
}

__device__ __forceinline__ float gelu_exact(float x){
  return 0.5f * x * (1.0f + erff(x * 0.70710678118654752f));
}

__device__ __forceinline__ f32x4 mfma16(bf16x8 a, bf16x8 b, f32x4 c){
  return __builtin_amdgcn_mfma_f32_16x16x32_bf16(a, b, c, 0, 0, 0);
}

// ---------------- weight transpose + fp32->bf16 convert ----------------
// W[K][N] fp32 -> Wt[N][K] bf16
__global__ __launch_bounds__(256) void tconv_kernel(
    const float* __restrict__ W, ushort_t* __restrict__ Wt, int K, int N)
{
  __shared__ float tile[32][33];
  int tx = threadIdx.x, ty = threadIdx.y;
  int n0 = blockIdx.x * 32, k0 = blockIdx.y * 32;
#pragma unroll
  for (int i = 0; i < 4; ++i)
    tile[ty + i*8][tx] = W[(size_t)(k0 + ty + i*8) * N + n0 + tx];
  __syncthreads();
#pragma unroll
  for (int i = 0; i < 4; ++i)
    Wt[(size_t)(n0 + ty + i*8) * K + k0 + tx] = f2b(tile[tx][ty + i*8]);
}

// ---------------- layernorm (fp32 in) -> bf16 out ----------------
__global__ __launch_bounds__(256) void ln_kernel(
    const float* __restrict__ x, const float* __restrict__ g,
    const float* __restrict__ bt, ushort_t* __restrict__ out)
{
  int row = blockIdx.x;
  int t = threadIdx.x;
  const float4 v = *(const float4*)&x[(size_t)row * DMODEL + t * 4];
  float s = v.x + v.y + v.z + v.w;
  float s2 = v.x*v.x + v.y*v.y + v.z*v.z + v.w*v.w;
#pragma unroll
  for (int d = 1; d < 64; d <<= 1) {
    s  += __shfl_xor(s,  d, 64);
    s2 += __shfl_xor(s2, d, 64);
  }
  __shared__ float red[8];
  int w = t >> 6;
  if ((t & 63) == 0) { red[w] = s; red[4 + w] = s2; }
  __syncthreads();
  s  = red[0] + red[1] + red[2] + red[3];
  s2 = red[4] + red[5] + red[6] + red[7];
  float mean = s * (1.0f / DMODEL);
  float var  = s2 * (1.0f / DMODEL) - mean * mean;
  float rstd = rsqrtf(var + 1e-5f);
  float4 gg = *(const float4*)&g[t * 4];
  float4 bb = *(const float4*)&bt[t * 4];
  ushort4 o;
  o.x = f2b((v.x - mean) * rstd * gg.x + bb.x);
  o.y = f2b((v.y - mean) * rstd * gg.y + bb.y);
  o.z = f2b((v.z - mean) * rstd * gg.z + bb.z);
  o.w = f2b((v.w - mean) * rstd * gg.w + bb.w);
  *(ushort4*)&out[(size_t)row * DMODEL + t * 4] = o;
}

// ---------------- generic bf16 GEMM: C[M,N] = A[M,K] @ Bt[N,K]^T ----------------
// MODE 0: out bf16 = acc + bias
// MODE 1: out bf16 -> vt[b][h][dh][s] per-head transposed, + bias
// MODE 2: out f32 = acc + bias + res
// MODE 3: out bf16 = gelu(acc + bias)
template<int MODE>
__global__ __launch_bounds__(256) void gemm_bt(
    const ushort_t* __restrict__ A, const ushort_t* __restrict__ Bt,
    const float* __restrict__ bias, const float* __restrict__ res,
    void* __restrict__ outp, int M, int N, int K)
{
  __shared__ ushort_t As[128 * 40];
  __shared__ ushort_t Bs[128 * 40];
  int t = threadIdx.x;
  int m0 = blockIdx.y * 128, n0 = blockIdx.x * 128;
  int w = t >> 6, l = t & 63, lr = l & 15, lg = l >> 4;
  int wr = (w >> 1) * 64, wc = (w & 1) * 64;
  f32x4 acc[4][4] = {};
  for (int k0 = 0; k0 < K; k0 += 32) {
#pragma unroll
    for (int it = 0; it < 2; ++it) {
      int idx = t + it * 256;
      int row = idx >> 2, cg = idx & 3;
      *(uint4*)&As[row * 40 + cg * 8] =
          *(const uint4*)&A[(size_t)(m0 + row) * K + k0 + cg * 8];
      *(uint4*)&Bs[row * 40 + cg * 8] =
          *(const uint4*)&Bt[(size_t)(n0 + row) * K + k0 + cg * 8];
    }
    __syncthreads();
    bf16x8 af[4], bf[4];
#pragma unroll
    for (int a = 0; a < 4; ++a)
      af[a] = *(const bf16x8*)&As[(wr + a * 16 + lr) * 40 + lg * 8];
#pragma unroll
    for (int b = 0; b < 4; ++b)
      bf[b] = *(const bf16x8*)&Bs[(wc + b * 16 + lr) * 40 + lg * 8];
#pragma unroll
    for (int a = 0; a < 4; ++a)
#pragma unroll
      for (int b = 0; b < 4; ++b)
        acc[a][b] = mfma16(af[a], bf[b], acc[a][b]);
    __syncthreads();
  }
  // epilogue; C row = (lane>>4)*4 + r, col = lane&15 (HW-verified layout)
  if (MODE == 0 || MODE == 3) {
    ushort_t* out = (ushort_t*)outp;
#pragma unroll
    for (int a = 0; a < 4; ++a)
#pragma unroll
      for (int b = 0; b < 4; ++b) {
        int gn = n0 + wc + b * 16 + lr;
        float bv = bias[gn];
#pragma unroll
        for (int r = 0; r < 4; ++r) {
          int gm = m0 + wr + a * 16 + lg * 4 + r;
          float vv = acc[a][b][r] + bv;
          if (MODE == 3) vv = gelu_exact(vv);
          out[(size_t)gm * N + gn] = f2b(vv);
        }
      }
  } else if (MODE == 2) {
    float* out = (float*)outp;
#pragma unroll
    for (int a = 0; a < 4; ++a)
#pragma unroll
      for (int b = 0; b < 4; ++b) {
        int gn = n0 + wc + b * 16 + lr;
        float bv = bias[gn];
#pragma unroll
        for (int r = 0; r < 4; ++r) {
          int gm = m0 + wr + a * 16 + lg * 4 + r;
          out[(size_t)gm * N + gn] = acc[a][b][r] + bv + res[(size_t)gm * N + gn];
        }
      }
  } else { // MODE 1: vt[b][h][dh][s]
    ushort_t* out = (ushort_t*)outp;
#pragma unroll
    for (int a = 0; a < 4; ++a)
#pragma unroll
      for (int b = 0; b < 4; ++b) {
        int gn = n0 + wc + b * 16 + lr;           // feature index -> (h, dh)
        int gm = m0 + wr + a * 16 + lg * 4;       // token index (r=0), 4 consecutive
        float bv = bias[gn];
        ushort4 pk;
        pk.x = f2b(acc[a][b][0] + bv);
        pk.y = f2b(acc[a][b][1] + bv);
        pk.z = f2b(acc[a][b][2] + bv);
        pk.w = f2b(acc[a][b][3] + bv);
        size_t addr = (((size_t)(gm >> 11) * NH + (gn >> 6)) * DH + (gn & 63)) * S_LEN
                      + (gm & (S_LEN - 1));
        *(ushort4*)&out[addr] = pk;
      }
  }
}

// ---------------- fused flash attention with relation bias ----------------
// q,k: [B][S][H][DH] bf16 ; vt: [B][H][DH][S] bf16 ; out att: [B][S][H][DH] bf16
__global__ __launch_bounds__(256) void attn_kernel(
    const ushort_t* __restrict__ q, const ushort_t* __restrict__ k,
    const ushort_t* __restrict__ vt,
    const float* __restrict__ ab, const float* __restrict__ mc,
    const unsigned char* __restrict__ kp,
    const float* __restrict__ Ws, const float* __restrict__ bs,
    const float* __restrict__ Wm, const float* __restrict__ bm,
    ushort_t* __restrict__ att)
{
  __shared__ ushort_t k_lds[64 * 80];
  __shared__ ushort_t v_lds[64 * 80];
  __shared__ ushort_t p_lds[4 * 16 * 80];
  int bh = blockIdx.y;
  int b = bh >> 4, h = bh & 15;
  int i0 = blockIdx.x * 64;
  int t = threadIdx.x, w = t >> 6, l = t & 63;
  int lr = l & 15, lg = l >> 4;
  float ws0 = Ws[h], ws1 = Ws[NH + h], ws2 = Ws[2 * NH + h];
  float bsh = bs[h], wmh = Wm[h], bmh = bm[h];
  const float scale = 0.125f;  // DH^-0.5

  int qrow = i0 + w * 16 + lr;
  size_t qbase = (size_t)(b * S_LEN + qrow) * DMODEL + h * DH;
  bf16x8 aq0 = *(const bf16x8*)&q[qbase + lg * 8];
  bf16x8 aq1 = *(const bf16x8*)&q[qbase + 32 + lg * 8];

  f32x4 acc_o[4] = {};
  float m_r[4], l_r[4];
#pragma unroll
  for (int r = 0; r < 4; ++r) { m_r[r] = -1e30f; l_r[r] = 0.0f; }

  for (int j0 = 0; j0 < S_LEN; j0 += 64) {
#pragma unroll
    for (int it = 0; it < 2; ++it) {
      int idx = t + it * 256;
      int row = idx >> 3, cg = idx & 7;
      *(uint4*)&k_lds[row * 80 + cg * 8] =
          *(const uint4*)&k[(size_t)(b * S_LEN + j0 + row) * DMODEL + h * DH + cg * 8];
      *(uint4*)&v_lds[row * 80 + cg * 8] =
          *(const uint4*)&vt[((size_t)(b * NH + h) * DH + row) * S_LEN + j0 + cg * 8];
    }
    __syncthreads();

    f32x4 acc_s[4] = {};
#pragma unroll
    for (int n = 0; n < 4; ++n) {
      bf16x8 b0 = *(const bf16x8*)&k_lds[(n * 16 + lr) * 80 + lg * 8];
      bf16x8 b1 = *(const bf16x8*)&k_lds[(n * 16 + lr) * 80 + 32 + lg * 8];
      acc_s[n] = mfma16(aq0, b0, acc_s[n]);
      acc_s[n] = mfma16(aq1, b1, acc_s[n]);
    }

    // bias + online softmax, one output row per (lg, r)
#pragma unroll
    for (int r = 0; r < 4; ++r) {
      int gr = i0 + w * 16 + lg * 4 + r;
      float pv[4];
#pragma unroll
      for (int n = 0; n < 4; ++n) {
        int gc = j0 + n * 16 + lr;
        size_t base = (size_t)(b * S_LEN + gr) * S_LEN + gc;
        float a0 = ab[base * 3], a1 = ab[base * 3 + 1], a2 = ab[base * 3 + 2];
        float mcv = mc[base];
        float val = acc_s[n][r] * scale + a0 * ws0 + a1 * ws1 + a2 * ws2 + bsh
                    + mcv * wmh + bmh;
        if (kp[b * S_LEN + gc]) val = -1e9f;
        pv[n] = val;
      }
      float mx = fmaxf(fmaxf(pv[0], pv[1]), fmaxf(pv[2], pv[3]));
#pragma unroll
      for (int d = 1; d < 16; d <<= 1) mx = fmaxf(mx, __shfl_xor(mx, d, 64));
      float mnew = fmaxf(m_r[r], mx);
      float sf = __expf(m_r[r] - mnew);
      float rs = 0.0f;
#pragma unroll
      for (int n = 0; n < 4; ++n) { pv[n] = __expf(pv[n] - mnew); rs += pv[n]; }
#pragma unroll
      for (int d = 1; d < 16; d <<= 1) rs += __shfl_xor(rs, d, 64);
      l_r[r] = l_r[r] * sf + rs;
      m_r[r] = mnew;
#pragma unroll
      for (int nd = 0; nd < 4; ++nd) acc_o[nd][r] *= sf;
#pragma unroll
      for (int n = 0; n < 4; ++n)
        p_lds[(w * 16 + lg * 4 + r) * 80 + n * 16 + lr] = f2b(pv[n]);
    }
    __syncthreads();

    // PV
    bf16x8 ap0 = *(const bf16x8*)&p_lds[(w * 16 + lr) * 80 + lg * 8];
    bf16x8 ap1 = *(const bf16x8*)&p_lds[(w * 16 + lr) * 80 + 32 + lg * 8];
#pragma unroll
    for (int nd = 0; nd < 4; ++nd) {
      bf16x8 b0 = *(const bf16x8*)&v_lds[(nd * 16 + lr) * 80 + lg * 8];
      bf16x8 b1 = *(const bf16x8*)&v_lds[(nd * 16 + lr) * 80 + 32 + lg * 8];
      acc_o[nd] = mfma16(ap0, b0, acc_o[nd]);
      acc_o[nd] = mfma16(ap1, b1, acc_o[nd]);
    }
    __syncthreads();
  }

#pragma unroll
  for (int r = 0; r < 4; ++r) {
    int gr = i0 + w * 16 + lg * 4 + r;
    float inv = 1.0f / l_r[r];
#pragma unroll
    for (int nd = 0; nd < 4; ++nd)
      att[(size_t)(b * S_LEN + gr) * DMODEL + h * DH + nd * 16 + lr] =
          f2b(acc_o[nd][r] * inv);
  }
}

// ---------------- host launch ----------------
extern "C" void kernel_launch(void* const* d_in, const int* in_sizes, int n_in,
                              void* d_out, int out_size, void* d_ws, size_t ws_size,
                              hipStream_t stream) {
  const float* tokens = (const float*)d_in[0];
  const float* ab     = (const float*)d_in[1];
  const float* mc     = (const float*)d_in[2];
  const unsigned char* kp = (const unsigned char*)d_in[3];
  const float* ln1g = (const float*)d_in[4];
  const float* ln1b = (const float*)d_in[5];
  const float* Wq = (const float*)d_in[6];
  const float* bq = (const float*)d_in[7];
  const float* Wk = (const float*)d_in[8];
  const float* bk = (const float*)d_in[9];
  const float* Wv = (const float*)d_in[10];
  const float* bv = (const float*)d_in[11];
  const float* Wo = (const float*)d_in[12];
  const float* bo = (const float*)d_in[13];
  const float* Ws = (const float*)d_in[14];
  const float* bs = (const float*)d_in[15];
  const float* Wm = (const float*)d_in[16];
  const float* bm = (const float*)d_in[17];
  const float* ln2g = (const float*)d_in[18];
  const float* ln2b = (const float*)d_in[19];
  const float* W1 = (const float*)d_in[20];
  const float* b1 = (const float*)d_in[21];
  const float* W2 = (const float*)d_in[22];
  const float* b2 = (const float*)d_in[23];
  float* out = (float*)d_out;

  int B = in_sizes[0] / (S_LEN * DMODEL);
  int M = B * S_LEN;

  char* ws = (char*)d_ws;
  // region A (reused as ff1 after attention): n, q, k, vt
  ushort_t* nb  = (ushort_t*)(ws + 0);
  ushort_t* qb  = (ushort_t*)(ws + (size_t)8388608);
  ushort_t* kb  = (ushort_t*)(ws + (size_t)16777216);
  ushort_t* vtb = (ushort_t*)(ws + (size_t)25165824);
  ushort_t* ff1 = (ushort_t*)(ws + 0);  // aliases n/q/k/vt (dead by then)
  // region B: transposed bf16 weights
  ushort_t* wt_q = (ushort_t*)(ws + (size_t)33554432);
  ushort_t* wt_k = (ushort_t*)(ws + (size_t)35651584);
  ushort_t* wt_v = (ushort_t*)(ws + (size_t)37748736);
  ushort_t* wt_o = (ushort_t*)(ws + (size_t)39845888);
  ushort_t* wt_1 = (ushort_t*)(ws + (size_t)41943040);
  ushort_t* wt_2 = (ushort_t*)(ws + (size_t)50331648);
  // region C
  ushort_t* attb = (ushort_t*)(ws + (size_t)58720256);
  float*    xb   = (float*)   (ws + (size_t)67108864);
  ushort_t* hb   = (ushort_t*)(ws + (size_t)83886080);

  dim3 tb(32, 8);
  tconv_kernel<<<dim3(32, 32), tb, 0, stream>>>(Wq, wt_q, DMODEL, DMODEL);
  tconv_kernel<<<dim3(32, 32), tb, 0, stream>>>(Wk, wt_k, DMODEL, DMODEL);
  tconv_kernel<<<dim3(32, 32), tb, 0, stream>>>(Wv, wt_v, DMODEL, DMODEL);
  tconv_kernel<<<dim3(32, 32), tb, 0, stream>>>(Wo, wt_o, DMODEL, DMODEL);
  tconv_kernel<<<dim3(128, 32), tb, 0, stream>>>(W1, wt_1, DMODEL, FFDIM);
  tconv_kernel<<<dim3(32, 128), tb, 0, stream>>>(W2, wt_2, FFDIM, DMODEL);

  ln_kernel<<<M, 256, 0, stream>>>(tokens, ln1g, ln1b, nb);

  gemm_bt<0><<<dim3(DMODEL / 128, M / 128), 256, 0, stream>>>(
      nb, wt_q, bq, nullptr, qb, M, DMODEL, DMODEL);
  gemm_bt<0><<<dim3(DMODEL / 128, M / 128), 256, 0, stream>>>(
      nb, wt_k, bk, nullptr, kb, M, DMODEL, DMODEL);
  gemm_bt<1><<<dim3(DMODEL / 128, M / 128), 256, 0, stream>>>(
      nb, wt_v, bv, nullptr, vtb, M, DMODEL, DMODEL);

  attn_kernel<<<dim3(S_LEN / 64, B * NH), 256, 0, stream>>>(
      qb, kb, vtb, ab, mc, kp, Ws, bs, Wm, bm, attb);

  gemm_bt<2><<<dim3(DMODEL / 128, M / 128), 256, 0, stream>>>(
      attb, wt_o, bo, tokens, xb, M, DMODEL, DMODEL);

  ln_kernel<<<M, 256, 0, stream>>>(xb, ln2g, ln2b, hb);

  gemm_bt<3><<<dim3(FFDIM / 128, M / 128), 256, 0, stream>>>(
      hb, wt_1, b1, nullptr, ff1, M, FFDIM, DMODEL);

  gemm_bt<2><<<dim3(DMODEL / 128, M / 128), 256, 0, stream>>>(
      ff1, wt_2, b2, xb, out, M, DMODEL, FFDIM);
}

// Round 2
// 758.704 us; speedup vs baseline: 1.1534x; 1.1534x over previous
//
#include <hip/hip_runtime.h>

#define S_LEN 2048
#define DMODEL 1024
#define NH 16
#define DH 64
#define FFDIM 4096

typedef __bf16 bf16x8 __attribute__((ext_vector_type(8)));
typedef float f32x4 __attribute__((ext_vector_type(4)));
typedef unsigned short ushort_t;

#define AS1 __attribute__((address_space(1)))
#define AS3 __attribute__((address_space(3)))

__device__ __forceinline__ void gll16(const void* g, void* l) {
  __builtin_amdgcn_global_load_lds((AS1 const void*)g, (AS3 void*)l, 16, 0, 0);
}

__device__ __forceinline__ unsigned short f2b(float f){
  unsigned u = __builtin_bit_cast(unsigned, f);
  u = (u + 0x7FFFu + ((u >> 16) & 1u)) >> 16;
  return (unsigned short)u;
}

__device__ __forceinline__ float b2f(unsigned short us){
  return __builtin_bit_cast(float, (unsigned)us << 16);
}

__device__ __forceinline__ float gelu_exact(float x){
  return 0.5f * x * (1.0f + erff(x * 0.70710678118654752f));
}

__device__ __forceinline__ f32x4 mfma16(bf16x8 a, bf16x8 b, f32x4 c){
  return __builtin_amdgcn_mfma_f32_16x16x32_bf16(a, b, c, 0, 0, 0);
}

// ---------------- weight transpose + fp32->bf16 convert ----------------
__global__ __launch_bounds__(256) void tconv_kernel(
    const float* __restrict__ W, ushort_t* __restrict__ Wt, int K, int N)
{
  __shared__ float tile[32][33];
  int tx = threadIdx.x, ty = threadIdx.y;
  int n0 = blockIdx.x * 32, k0 = blockIdx.y * 32;
#pragma unroll
  for (int i = 0; i < 4; ++i)
    tile[ty + i*8][tx] = W[(size_t)(k0 + ty + i*8) * N + n0 + tx];
  __syncthreads();
#pragma unroll
  for (int i = 0; i < 4; ++i)
    Wt[(size_t)(n0 + ty + i*8) * K + k0 + tx] = f2b(tile[tx][ty + i*8]);
}

// ---------------- layernorm (fp32 in) -> bf16 out ----------------
__global__ __launch_bounds__(256) void ln_kernel(
    const float* __restrict__ x, const float* __restrict__ g,
    const float* __restrict__ bt, ushort_t* __restrict__ out)
{
  int row = blockIdx.x;
  int t = threadIdx.x;
  const float4 v = *(const float4*)&x[(size_t)row * DMODEL + t * 4];
  float s = v.x + v.y + v.z + v.w;
  float s2 = v.x*v.x + v.y*v.y + v.z*v.z + v.w*v.w;
#pragma unroll
  for (int d = 1; d < 64; d <<= 1) {
    s  += __shfl_xor(s,  d, 64);
    s2 += __shfl_xor(s2, d, 64);
  }
  __shared__ float red[8];
  int w = t >> 6;
  if ((t & 63) == 0) { red[w] = s; red[4 + w] = s2; }
  __syncthreads();
  s  = red[0] + red[1] + red[2] + red[3];
  s2 = red[4] + red[5] + red[6] + red[7];
  float mean = s * (1.0f / DMODEL);
  float var  = s2 * (1.0f / DMODEL) - mean * mean;
  float rstd = rsqrtf(var + 1e-5f);
  float4 gg = *(const float4*)&g[t * 4];
  float4 bb = *(const float4*)&bt[t * 4];
  ushort4 o;
  o.x = f2b((v.x - mean) * rstd * gg.x + bb.x);
  o.y = f2b((v.y - mean) * rstd * gg.y + bb.y);
  o.z = f2b((v.z - mean) * rstd * gg.z + bb.z);
  o.w = f2b((v.w - mean) * rstd * gg.w + bb.w);
  *(ushort4*)&out[(size_t)row * DMODEL + t * 4] = o;
}

// ---------------- bias precompute: per-head bf16 [B][H][S][S] ----------------
__global__ __launch_bounds__(256) void bias_head_kernel(
    const float* __restrict__ ab, const float* __restrict__ mc,
    const unsigned char* __restrict__ kp,
    const float* __restrict__ Ws, const float* __restrict__ bs,
    const float* __restrict__ Wm, const float* __restrict__ bm,
    ushort_t* __restrict__ bp)
{
  int bi = blockIdx.x;            // b*S + i
  int b = bi >> 11;
  int i = bi & (S_LEN - 1);
  int t = threadIdx.x;
  int j0 = t * 8;
  float av[24];
  const float4* A4 = (const float4*)(ab + ((size_t)bi * S_LEN + j0) * 3);
#pragma unroll
  for (int u = 0; u < 6; ++u) {
    float4 x = A4[u];
    av[u*4] = x.x; av[u*4+1] = x.y; av[u*4+2] = x.z; av[u*4+3] = x.w;
  }
  float mv[8];
  const float4* M4 = (const float4*)(mc + (size_t)bi * S_LEN + j0);
#pragma unroll
  for (int u = 0; u < 2; ++u) {
    float4 x = M4[u];
    mv[u*4] = x.x; mv[u*4+1] = x.y; mv[u*4+2] = x.z; mv[u*4+3] = x.w;
  }
  unsigned long long kq = *(const unsigned long long*)(kp + (size_t)b * S_LEN + j0);
#pragma unroll
  for (int h = 0; h < NH; ++h) {
    float w0 = Ws[h], w1 = Ws[NH + h], w2 = Ws[2*NH + h];
    float wm = Wm[h], cc = bs[h] + bm[h];
    alignas(16) ushort_t o[8];
#pragma unroll
    for (int j = 0; j < 8; ++j) {
      float v = av[j*3]*w0 + av[j*3+1]*w1 + av[j*3+2]*w2 + mv[j]*wm + cc;
      if ((kq >> (8*j)) & 1ull) v = -1e9f;
      o[j] = f2b(v);
    }
    *(uint4*)&bp[((size_t)(b*NH + h) * S_LEN + i) * S_LEN + j0] = *(const uint4*)o;
  }
}

// ---------------- bias precompute fallback: packed bf16x4 [B][S][S][4] ----------------
__global__ __launch_bounds__(256) void bias_pack4_kernel(
    const float* __restrict__ ab, const float* __restrict__ mc,
    ushort_t* __restrict__ bp4)
{
  int bi = blockIdx.x;
  int t = threadIdx.x;
  int j0 = t * 8;
  const float4* A4 = (const float4*)(ab + ((size_t)bi * S_LEN + j0) * 3);
  float av[24];
#pragma unroll
  for (int u = 0; u < 6; ++u) {
    float4 x = A4[u];
    av[u*4] = x.x; av[u*4+1] = x.y; av[u*4+2] = x.z; av[u*4+3] = x.w;
  }
  float mv[8];
  const float4* M4 = (const float4*)(mc + (size_t)bi * S_LEN + j0);
#pragma unroll
  for (int u = 0; u < 2; ++u) {
    float4 x = M4[u];
    mv[u*4] = x.x; mv[u*4+1] = x.y; mv[u*4+2] = x.z; mv[u*4+3] = x.w;
  }
  alignas(16) ushort_t o[32];
#pragma unroll
  for (int j = 0; j < 8; ++j) {
    o[j*4]   = f2b(av[j*3]);
    o[j*4+1] = f2b(av[j*3+1]);
    o[j*4+2] = f2b(av[j*3+2]);
    o[j*4+3] = f2b(mv[j]);
  }
  uint4* dst = (uint4*)&bp4[((size_t)bi * S_LEN + j0) * 4];
#pragma unroll
  for (int u = 0; u < 4; ++u) dst[u] = ((const uint4*)o)[u];
}

// ---------------- generic bf16 GEMM: C[M,N] = A[M,K] @ Bt[N,K]^T ----------------
// m97 structure: 128x128 tile, BK=32, global_load_lds width-16, 2-barrier loop.
// MODE 2: out f32 = acc + bias + res
// MODE 3: out bf16 = gelu(acc + bias)
// MODE 4: fused QKV: N=3072; seg0->o0 bf16 [M][1024], seg1->o1 bf16, seg2->o2 vt layout
template<int MODE>
__global__ __launch_bounds__(256) void gemm_bt(
    const ushort_t* __restrict__ A, const ushort_t* __restrict__ Bt,
    const float* __restrict__ b0p, const float* __restrict__ b1p,
    const float* __restrict__ b2p, const float* __restrict__ res,
    void* __restrict__ o0, void* __restrict__ o1, void* __restrict__ o2,
    int M, int N, int K)
{
  __shared__ ushort_t sh[8192];   // bytes [0,8192) = A tile [128][32]; [8192,16384) = B tile
  int t = threadIdx.x;
  int m0 = blockIdx.y * 128, n0 = blockIdx.x * 128;
  int w = t >> 6, l = t & 63, lr = l & 15, lg = l >> 4;
  int wr = (w >> 1) * 64, wc = (w & 1) * 64;

  const ushort_t* srcp[4];
  ushort_t* dstp[4];
#pragma unroll
  for (int j = 0; j < 4; ++j) {
    int c = j * 4 + w;
    int o = c * 1024 + l * 16;          // byte offset in sh
    if (c < 8)
      srcp[j] = &A[(size_t)(m0 + (o >> 6)) * K + ((o & 63) >> 1)];
    else {
      int o2 = o - 8192;
      srcp[j] = &Bt[(size_t)(n0 + (o2 >> 6)) * K + ((o2 & 63) >> 1)];
    }
    dstp[j] = (ushort_t*)((char*)sh + o);
  }

  f32x4 acc[4][4] = {};
  for (int k0 = 0; k0 < K; k0 += 32) {
#pragma unroll
    for (int j = 0; j < 4; ++j) gll16(srcp[j] + k0, dstp[j]);
    __syncthreads();
    bf16x8 af[4], bfr[4];
#pragma unroll
    for (int a = 0; a < 4; ++a)
      af[a] = *(const bf16x8*)&sh[(wr + a * 16 + lr) * 32 + lg * 8];
#pragma unroll
    for (int b = 0; b < 4; ++b)
      bfr[b] = *(const bf16x8*)&sh[4096 + (wc + b * 16 + lr) * 32 + lg * 8];
#pragma unroll
    for (int a = 0; a < 4; ++a)
#pragma unroll
      for (int b = 0; b < 4; ++b)
        acc[a][b] = mfma16(af[a], bfr[b], acc[a][b]);
    __syncthreads();
  }

  // epilogue; C row = (lane>>4)*4 + r, col = lane&15
  if (MODE == 2) {
    float* out = (float*)o0;
#pragma unroll
    for (int a = 0; a < 4; ++a)
#pragma unroll
      for (int b = 0; b < 4; ++b) {
        int gn = n0 + wc + b * 16 + lr;
        float bv = b0p[gn];
#pragma unroll
        for (int r = 0; r < 4; ++r) {
          int gm = m0 + wr + a * 16 + lg * 4 + r;
          out[(size_t)gm * N + gn] = acc[a][b][r] + bv + res[(size_t)gm * N + gn];
        }
      }
  } else if (MODE == 3) {
    ushort_t* out = (ushort_t*)o0;
#pragma unroll
    for (int a = 0; a < 4; ++a)
#pragma unroll
      for (int b = 0; b < 4; ++b) {
        int gn = n0 + wc + b * 16 + lr;
        float bv = b0p[gn];
#pragma unroll
        for (int r = 0; r < 4; ++r) {
          int gm = m0 + wr + a * 16 + lg * 4 + r;
          out[(size_t)gm * N + gn] = f2b(gelu_exact(acc[a][b][r] + bv));
        }
      }
  } else { // MODE 4
    int seg = n0 >> 10;                 // uniform per block (1024 % 128 == 0)
    int nb0 = n0 & 1023;
    const float* bi = (seg == 0) ? b0p : (seg == 1) ? b1p : b2p;
    if (seg < 2) {
      ushort_t* out = (ushort_t*)((seg == 0) ? o0 : o1);
#pragma unroll
      for (int a = 0; a < 4; ++a)
#pragma unroll
        for (int b = 0; b < 4; ++b) {
          int nn = nb0 + wc + b * 16 + lr;
          float bv = bi[nn];
#pragma unroll
          for (int r = 0; r < 4; ++r) {
            int gm = m0 + wr + a * 16 + lg * 4 + r;
            out[(size_t)gm * DMODEL + nn] = f2b(acc[a][b][r] + bv);
          }
        }
    } else {
      ushort_t* out = (ushort_t*)o2;    // vt[b][h][dh][s]
#pragma unroll
      for (int a = 0; a < 4; ++a)
#pragma unroll
        for (int b = 0; b < 4; ++b) {
          int nn = nb0 + wc + b * 16 + lr;
          int gm = m0 + wr + a * 16 + lg * 4;
          float bv = bi[nn];
          ushort4 pk;
          pk.x = f2b(acc[a][b][0] + bv);
          pk.y = f2b(acc[a][b][1] + bv);
          pk.z = f2b(acc[a][b][2] + bv);
          pk.w = f2b(acc[a][b][3] + bv);
          size_t addr = (((size_t)(gm >> 11) * NH + (nn >> 6)) * DH + (nn & 63)) * S_LEN
                        + (gm & (S_LEN - 1));
          *(ushort4*)&out[addr] = pk;
        }
    }
  }
}

// ---------------- fused flash attention ----------------
// BMODE 0: per-head bf16 bias bp[b][h][i][j]
// BMODE 1: packed bf16x4 bp4[b][i][j][4] + per-head weights + kp
// BMODE 2: raw fp32 ab/mc/kp (no scratch)
template<int BMODE>
__global__ __launch_bounds__(256) void attn_kernel(
    const ushort_t* __restrict__ q, const ushort_t* __restrict__ k,
    const ushort_t* __restrict__ vt,
    const ushort_t* __restrict__ bp,
    const float* __restrict__ ab, const float* __restrict__ mc,
    const unsigned char* __restrict__ kp,
    const float* __restrict__ Ws, const float* __restrict__ bs,
    const float* __restrict__ Wm, const float* __restrict__ bm,
    ushort_t* __restrict__ att)
{
  __shared__ ushort_t k_lds[64 * 80];
  __shared__ ushort_t v_lds[64 * 80];
  __shared__ ushort_t p_lds[4 * 16 * 80];
  int bh = blockIdx.y;
  int b = bh >> 4, h = bh & 15;
  int i0 = blockIdx.x * 64;
  int t = threadIdx.x, w = t >> 6, l = t & 63;
  int lr = l & 15, lg = l >> 4;
  float ws0 = 0, ws1 = 0, ws2 = 0, wmh = 0, cc = 0;
  if (BMODE != 0) {
    ws0 = Ws[h]; ws1 = Ws[NH + h]; ws2 = Ws[2 * NH + h];
    wmh = Wm[h]; cc = bs[h] + bm[h];
  }
  const float scale = 0.125f;

  int qrow = i0 + w * 16 + lr;
  size_t qbase = (size_t)(b * S_LEN + qrow) * DMODEL + h * DH;
  bf16x8 aq0 = *(const bf16x8*)&q[qbase + lg * 8];
  bf16x8 aq1 = *(const bf16x8*)&q[qbase + 32 + lg * 8];

  f32x4 acc_o[4] = {};
  float m_r[4], l_r[4];
#pragma unroll
  for (int r = 0; r < 4; ++r) { m_r[r] = -1e30f; l_r[r] = 0.0f; }

  for (int j0 = 0; j0 < S_LEN; j0 += 64) {
#pragma unroll
    for (int it = 0; it < 2; ++it) {
      int idx = t + it * 256;
      int row = idx >> 3, cg = idx & 7;
      *(uint4*)&k_lds[row * 80 + cg * 8] =
          *(const uint4*)&k[(size_t)(b * S_LEN + j0 + row) * DMODEL + h * DH + cg * 8];
      *(uint4*)&v_lds[row * 80 + cg * 8] =
          *(const uint4*)&vt[((size_t)(b * NH + h) * DH + row) * S_LEN + j0 + cg * 8];
    }
    __syncthreads();

    f32x4 acc_s[4] = {};
#pragma unroll
    for (int n = 0; n < 4; ++n) {
      bf16x8 b0 = *(const bf16x8*)&k_lds[(n * 16 + lr) * 80 + lg * 8];
      bf16x8 b1 = *(const bf16x8*)&k_lds[(n * 16 + lr) * 80 + 32 + lg * 8];
      acc_s[n] = mfma16(aq0, b0, acc_s[n]);
      acc_s[n] = mfma16(aq1, b1, acc_s[n]);
    }

    bool kpm[4] = {false, false, false, false};
    if (BMODE == 1 || BMODE == 2) {
#pragma unroll
      for (int n = 0; n < 4; ++n) kpm[n] = kp[b * S_LEN + j0 + n * 16 + lr];
    }

#pragma unroll
    for (int r = 0; r < 4; ++r) {
      int gr = i0 + w * 16 + lg * 4 + r;
      float pv[4];
      if (BMODE == 0) {
        size_t rb = ((size_t)bh * S_LEN + gr) * S_LEN + j0;
#pragma unroll
        for (int n = 0; n < 4; ++n) {
          float bv = b2f(bp[rb + n * 16 + lr]);
          pv[n] = fmaf(acc_s[n][r], scale, bv);
        }
      } else if (BMODE == 1) {
        size_t rb = ((size_t)(b * S_LEN + gr) * S_LEN + j0) * 4;
#pragma unroll
        for (int n = 0; n < 4; ++n) {
          const uint2 raw = *(const uint2*)&bp[rb + (size_t)(n * 16 + lr) * 4];
          float a0 = b2f((unsigned short)(raw.x & 0xFFFF));
          float a1 = b2f((unsigned short)(raw.x >> 16));
          float a2 = b2f((unsigned short)(raw.y & 0xFFFF));
          float mm = b2f((unsigned short)(raw.y >> 16));
          float v = fmaf(acc_s[n][r], scale,
                         a0 * ws0 + a1 * ws1 + a2 * ws2 + mm * wmh + cc);
          if (kpm[n]) v = -1e9f;
          pv[n] = v;
        }
      } else {
        size_t rb = (size_t)(b * S_LEN + gr) * S_LEN + j0;
#pragma unroll
        for (int n = 0; n < 4; ++n) {
          size_t base = rb + n * 16 + lr;
          float a0 = ab[base * 3], a1 = ab[base * 3 + 1], a2 = ab[base * 3 + 2];
          float mcv = mc[base];
          float v = fmaf(acc_s[n][r], scale,
                         a0 * ws0 + a1 * ws1 + a2 * ws2 + mcv * wmh + cc);
          if (kpm[n]) v = -1e9f;
          pv[n] = v;
        }
      }
      float mx = fmaxf(fmaxf(pv[0], pv[1]), fmaxf(pv[2], pv[3]));
#pragma unroll
      for (int d = 1; d < 16; d <<= 1) mx = fmaxf(mx, __shfl_xor(mx, d, 64));
      float mnew = fmaxf(m_r[r], mx);
      float sf = __expf(m_r[r] - mnew);
      float rs = 0.0f;
#pragma unroll
      for (int n = 0; n < 4; ++n) { pv[n] = __expf(pv[n] - mnew); rs += pv[n]; }
#pragma unroll
      for (int d = 1; d < 16; d <<= 1) rs += __shfl_xor(rs, d, 64);
      l_r[r] = l_r[r] * sf + rs;
      m_r[r] = mnew;
#pragma unroll
      for (int nd = 0; nd < 4; ++nd) acc_o[nd][r] *= sf;
#pragma unroll
      for (int n = 0; n < 4; ++n)
        p_lds[(w * 16 + lg * 4 + r) * 80 + n * 16 + lr] = f2b(pv[n]);
    }
    __syncthreads();

    bf16x8 ap0 = *(const bf16x8*)&p_lds[(w * 16 + lr) * 80 + lg * 8];
    bf16x8 ap1 = *(const bf16x8*)&p_lds[(w * 16 + lr) * 80 + 32 + lg * 8];
#pragma unroll
    for (int nd = 0; nd < 4; ++nd) {
      bf16x8 b0 = *(const bf16x8*)&v_lds[(nd * 16 + lr) * 80 + lg * 8];
      bf16x8 b1 = *(const bf16x8*)&v_lds[(nd * 16 + lr) * 80 + 32 + lg * 8];
      acc_o[nd] = mfma16(ap0, b0, acc_o[nd]);
      acc_o[nd] = mfma16(ap1, b1, acc_o[nd]);
    }
    __syncthreads();
  }

#pragma unroll
  for (int r = 0; r < 4; ++r) {
    int gr = i0 + w * 16 + lg * 4 + r;
    float inv = 1.0f / l_r[r];
#pragma unroll
    for (int nd = 0; nd < 4; ++nd)
      att[(size_t)(b * S_LEN + gr) * DMODEL + h * DH + nd * 16 + lr] =
          f2b(acc_o[nd][r] * inv);
  }
}

// ---------------- host launch ----------------
extern "C" void kernel_launch(void* const* d_in, const int* in_sizes, int n_in,
                              void* d_out, int out_size, void* d_ws, size_t ws_size,
                              hipStream_t stream) {
  const float* tokens = (const float*)d_in[0];
  const float* ab     = (const float*)d_in[1];
  const float* mc     = (const float*)d_in[2];
  const unsigned char* kp = (const unsigned char*)d_in[3];
  const float* ln1g = (const float*)d_in[4];
  const float* ln1b = (const float*)d_in[5];
  const float* Wq = (const float*)d_in[6];
  const float* bq = (const float*)d_in[7];
  const float* Wk = (const float*)d_in[8];
  const float* bk = (const float*)d_in[9];
  const float* Wv = (const float*)d_in[10];
  const float* bv = (const float*)d_in[11];
  const float* Wo = (const float*)d_in[12];
  const float* bo = (const float*)d_in[13];
  const float* Ws = (const float*)d_in[14];
  const float* bs = (const float*)d_in[15];
  const float* Wm = (const float*)d_in[16];
  const float* bm = (const float*)d_in[17];
  const float* ln2g = (const float*)d_in[18];
  const float* ln2b = (const float*)d_in[19];
  const float* W1 = (const float*)d_in[20];
  const float* b1 = (const float*)d_in[21];
  const float* W2 = (const float*)d_in[22];
  const float* b2 = (const float*)d_in[23];
  float* out = (float*)d_out;

  int B = in_sizes[0] / (S_LEN * DMODEL);
  int M = B * S_LEN;

  char* ws = (char*)d_ws;
  ushort_t* nb  = (ushort_t*)(ws + 0);
  ushort_t* qb  = (ushort_t*)(ws + (size_t)8388608);
  ushort_t* kb  = (ushort_t*)(ws + (size_t)16777216);
  ushort_t* vtb = (ushort_t*)(ws + (size_t)25165824);
  ushort_t* ff1 = (ushort_t*)(ws + 0);  // aliases n/q/k/vt (dead by then)
  ushort_t* wt_q = (ushort_t*)(ws + (size_t)33554432);  // wt_q/k/v contiguous [3072][1024]
  ushort_t* wt_k = (ushort_t*)(ws + (size_t)35651584);
  ushort_t* wt_v = (ushort_t*)(ws + (size_t)37748736);
  ushort_t* wt_o = (ushort_t*)(ws + (size_t)39845888);
  ushort_t* wt_1 = (ushort_t*)(ws + (size_t)41943040);
  ushort_t* wt_2 = (ushort_t*)(ws + (size_t)50331648);
  ushort_t* attb = (ushort_t*)(ws + (size_t)58720256);
  float*    xb   = (float*)   (ws + (size_t)67108864);
  ushort_t* hb   = (ushort_t*)(ws + (size_t)83886080);
  ushort_t* bp   = (ushort_t*)(ws + (size_t)92274688);

  size_t need_head  = 92274688ULL + (size_t)B * NH * S_LEN * S_LEN * 2;  // ~360 MB
  size_t need_pack4 = 92274688ULL + (size_t)B * S_LEN * S_LEN * 8;       // ~160 MB
  int bias_mode = (ws_size >= need_head) ? 0 : (ws_size >= need_pack4) ? 1 : 2;

  dim3 tb(32, 8);
  tconv_kernel<<<dim3(32, 32), tb, 0, stream>>>(Wq, wt_q, DMODEL, DMODEL);
  tconv_kernel<<<dim3(32, 32), tb, 0, stream>>>(Wk, wt_k, DMODEL, DMODEL);
  tconv_kernel<<<dim3(32, 32), tb, 0, stream>>>(Wv, wt_v, DMODEL, DMODEL);
  tconv_kernel<<<dim3(32, 32), tb, 0, stream>>>(Wo, wt_o, DMODEL, DMODEL);
  tconv_kernel<<<dim3(128, 32), tb, 0, stream>>>(W1, wt_1, DMODEL, FFDIM);
  tconv_kernel<<<dim3(32, 128), tb, 0, stream>>>(W2, wt_2, FFDIM, DMODEL);

  ln_kernel<<<M, 256, 0, stream>>>(tokens, ln1g, ln1b, nb);

  if (bias_mode == 0)
    bias_head_kernel<<<M, 256, 0, stream>>>(ab, mc, kp, Ws, bs, Wm, bm, bp);
  else if (bias_mode == 1)
    bias_pack4_kernel<<<M, 256, 0, stream>>>(ab, mc, bp);

  // fused QKV GEMM: N = 3072
  gemm_bt<4><<<dim3(24, M / 128), 256, 0, stream>>>(
      nb, wt_q, bq, bk, bv, nullptr, qb, kb, vtb, M, 3 * DMODEL, DMODEL);

  dim3 ag(S_LEN / 64, B * NH);
  if (bias_mode == 0)
    attn_kernel<0><<<ag, 256, 0, stream>>>(qb, kb, vtb, bp, ab, mc, kp,
                                           Ws, bs, Wm, bm, attb);
  else if (bias_mode == 1)
    attn_kernel<1><<<ag, 256, 0, stream>>>(qb, kb, vtb, bp, ab, mc, kp,
                                           Ws, bs, Wm, bm, attb);
  else
    attn_kernel<2><<<ag, 256, 0, stream>>>(qb, kb, vtb, nullptr, ab, mc, kp,
                                           Ws, bs, Wm, bm, attb);

  gemm_bt<2><<<dim3(8, M / 128), 256, 0, stream>>>(
      attb, wt_o, bo, nullptr, nullptr, tokens, xb, nullptr, nullptr,
      M, DMODEL, DMODEL);

  ln_kernel<<<M, 256, 0, stream>>>(xb, ln2g, ln2b, hb);

  gemm_bt<3><<<dim3(32, M / 128), 256, 0, stream>>>(
      hb, wt_1, b1, nullptr, nullptr, nullptr, ff1, nullptr, nullptr,
      M, FFDIM, DMODEL);

  gemm_bt<2><<<dim3(8, M / 128), 256, 0, stream>>>(
      ff1, wt_2, b2, nullptr, nullptr, xb, out, nullptr, nullptr,
      M, DMODEL, FFDIM);
}